// Round 12
// baseline (159.188 us; speedup 1.0000x reference)
//
#include <hip/hip_runtime.h>

#define MDIM 512
#define NDIM 8192
#define KDIM 8192

typedef float v4f __attribute__((ext_vector_type(4)));
typedef int   v4i __attribute__((ext_vector_type(4)));
typedef char  c16 __attribute__((ext_vector_type(16)));

#define GLDS16(g, l)                                                    \
  __builtin_amdgcn_global_load_lds(                                     \
      (const __attribute__((address_space(1))) void*)(g),               \
      (__attribute__((address_space(3))) void*)(l), 16, 0, 0)
#define SB __builtin_amdgcn_sched_barrier(0)

// Swizzled byte offset inside a tile of 64B rows (BK=64 int8): rows paired
// into 128B blocks of 8x16B slots; slot XOR'd with row-pair (r8 scheme,
// measured 0 conflicts). Producers write this layout; glds copies linearly;
// gemm ds_read applies the same formula (rule 21: both sides).
__device__ __forceinline__ int swb(int row, int g) {
  return ((row >> 1) << 7) + (((((row & 1) << 2) | g) ^ ((row >> 1) & 7)) << 4);
}

// Merged producer:
//  blocks [0, 16384): wq int32 -> int8, tiled w8[nt128][kt128][4KB], swizzled.
//  blocks [16384, 16896): x fp32 -> int8 + per-row scale ax, xq tiled.
__global__ __launch_bounds__(256) void produce_kernel(
    const int* __restrict__ wq, const float* __restrict__ x,
    char* __restrict__ w8, char* __restrict__ xq, float* __restrict__ ax) {
  if (blockIdx.x < 16384) {
    const int tid = blockIdx.x * 256 + threadIdx.x;
    const int R = tid >> 9;     // weight row 0..8191
    const int k16 = tid & 511;  // 16-int group
    const int* src = wq + ((size_t)R << 13) + k16 * 16;
    v4i a[4];
#pragma unroll
    for (int h = 0; h < 4; ++h) a[h] = *(const v4i*)(src + h * 4);
    c16 q;
#pragma unroll
    for (int h = 0; h < 4; ++h) {
      q[h * 4 + 0] = (char)a[h][0];
      q[h * 4 + 1] = (char)a[h][1];
      q[h * 4 + 2] = (char)a[h][2];
      q[h * 4 + 3] = (char)a[h][3];
    }
    const int nt = R >> 6, r = R & 63;
    const int kt = k16 >> 2, g = k16 & 3;
    *(c16*)(w8 + ((size_t)(nt * 128 + kt) << 12) + swb(r, g)) = q;
  } else {
    const int m = blockIdx.x - 16384;
    const int t = threadIdx.x;
    const float* row = x + ((size_t)m << 13);
    v4f v[8];
    float mx = 0.f;
#pragma unroll
    for (int i = 0; i < 8; ++i) {
      v[i] = *(const v4f*)(row + t * 32 + i * 4);
#pragma unroll
      for (int r = 0; r < 4; ++r) mx = fmaxf(mx, fabsf(v[i][r]));
    }
#pragma unroll
    for (int d = 1; d < 64; d <<= 1) mx = fmaxf(mx, __shfl_xor(mx, d));
    __shared__ float smx[4];
    if ((t & 63) == 0) smx[t >> 6] = mx;
    __syncthreads();
    mx = fmaxf(fmaxf(smx[0], smx[1]), fmaxf(smx[2], smx[3]));
    const float inv = (mx > 0.f) ? 127.f / mx : 0.f;
    if (t == 0) ax[m] = mx / 127.f;
    const int mt = m >> 7, r = m & 127;
#pragma unroll
    for (int g2 = 0; g2 < 2; ++g2) {
      c16 q;
#pragma unroll
      for (int e = 0; e < 16; ++e) {
        const int idx = g2 * 4 + (e >> 2);
        float f = fminf(fmaxf(v[idx][e & 3] * inv, -127.f), 127.f);
        q[e] = (char)__float2int_rn(f);
      }
      const int k16 = t * 2 + g2;
      const int kt = k16 >> 2, g = k16 & 3;
      *(c16*)(xq + ((size_t)(mt * 128 + kt) << 13) + swb(r, g)) = q;
    }
  }
}

template <int KS>
__global__ __launch_bounds__(256) void reduce_kernel(const float* __restrict__ p,
                                                     float* __restrict__ out) {
  const size_t i = ((size_t)blockIdx.x * 256 + threadIdx.x) * 4;
  v4f a = *(const v4f*)(p + i);
#pragma unroll
  for (int s = 1; s < KS; ++s) a += *(const v4f*)(p + (size_t)s * MDIM * NDIM + i);
  *(v4f*)(out + i) = a;
}

// Pure-i8 GEMM, r8 structure EXACT (best measured): BM=128 BN=64 BK=64,
// double-buffered LDS (24KB), counted vmcnt(3), 4 waves (64m x 32n each).
// Per phase/wave: 3 glds, 6 ds_read_b128, 8 mfma_i32_16x16x64_i8; scale
// fold per k128 (2 phases); ax at epilogue. KS-way split-K for block TLP.
template <int KS>
__global__ __launch_bounds__(256, 4) void gemm_i8_kernel(
    const char* __restrict__ xq, const char* __restrict__ w8,
    const float* __restrict__ wsc, const float* __restrict__ ax,
    float* __restrict__ outp) {
  constexpr int NKT = 128 / KS;  // k64 phases per block (even)
  __shared__ char lA[2][8192];
  __shared__ char lB[2][4096];

  // XCD swizzle: XCD c owns nt in [c*16, c*16+16) x all mt,kh -> each
  // weight tile served to its 4*KS consumer blocks from that XCD's L2/L3.
  const int b = blockIdx.x;
  const int c = b & 7;
  const int s = b >> 3;
  const int mt = s & 3;
  const int kh = (KS > 1) ? ((s >> 2) & (KS - 1)) : 0;
  const int nt = c * 16 + ((KS > 1) ? (s >> (2 + (KS == 2 ? 1 : 2))) : (s >> 2));
  const int m0 = mt * 128, n0 = nt * 64;
  const int kt0 = kh * NKT;  // global k64-tile base

  const int t = threadIdx.x;
  const int w = t >> 6, l = t & 63;
  const int wm = (w >> 1) * 64, wn = (w & 1) * 32;
  const int l15 = l & 15, q = l >> 4;

  const char* asrc = xq + ((size_t)(mt * 128 + kt0) << 13);
  const char* bsrc = w8 + ((size_t)(nt * 128 + kt0) << 12);

  v4i acc[4][2] = {};
  v4f facc[4][2] = {};

  auto issue = [&](int tt) {
    const int buf = tt & 1;
#pragma unroll
    for (int it = 0; it < 2; ++it) {
      const int ub = (it * 4 + w) * 64;  // wave-uniform 16B-unit base
      GLDS16(asrc + ((size_t)tt << 13) + (size_t)(ub + l) * 16, &lA[buf][ub * 16]);
    }
    GLDS16(bsrc + ((size_t)tt << 12) + (size_t)(w * 64 + l) * 16, &lB[buf][w * 1024]);
  };

  issue(0);
#pragma unroll 1
  for (int tt = 0; tt < NKT; ++tt) {
    const int cur = tt & 1;
    SB;
    __builtin_amdgcn_s_barrier();  // all waves done reading buf[cur^1]
    SB;
    if (tt + 1 < NKT) issue(tt + 1);  // -> buf[cur^1], stays in flight
    SB;
    if (tt + 1 < NKT)
      asm volatile("s_waitcnt vmcnt(3)" ::: "memory");  // tile tt landed
    else
      asm volatile("s_waitcnt vmcnt(0)" ::: "memory");
    SB;
    __builtin_amdgcn_s_barrier();  // buf[cur] visible to all waves
    SB;

    v4i af[4], bq[2];
#pragma unroll
    for (int i = 0; i < 4; ++i)
      af[i] = *(const v4i*)&lA[cur][swb(wm + i * 16 + l15, q)];
#pragma unroll
    for (int j = 0; j < 2; ++j)
      bq[j] = *(const v4i*)&lB[cur][swb(wn + j * 16 + l15, q)];
#pragma unroll
    for (int i = 0; i < 4; ++i)
#pragma unroll
      for (int j = 0; j < 2; ++j)
        acc[i][j] = __builtin_amdgcn_mfma_i32_16x16x64_i8(
            af[i], bq[j], acc[i][j], 0, 0, 0);

    if (tt & 1) {  // per-k128 scale block -> fold into f32 accumulator
      const float sc = wsc[(nt >> 1) * 64 + ((kt0 + tt) >> 1)];
#pragma unroll
      for (int i = 0; i < 4; ++i)
#pragma unroll
        for (int j = 0; j < 2; ++j) {
#pragma unroll
          for (int r = 0; r < 4; ++r)
            facc[i][j][r] = fmaf(sc, (float)acc[i][j][r], facc[i][j][r]);
          acc[i][j] = v4i{0, 0, 0, 0};
        }
    }
  }

  float* dst = outp + ((KS > 1) ? (size_t)kh * MDIM * NDIM : 0);
#pragma unroll
  for (int i = 0; i < 4; ++i) {
    const int mrow = m0 + wm + i * 16 + (l >> 4) * 4;
#pragma unroll
    for (int j = 0; j < 2; ++j) {
      const int ocol = n0 + wn + j * 16 + l15;
#pragma unroll
      for (int r = 0; r < 4; ++r)
        dst[(size_t)(mrow + r) * NDIM + ocol] = ax[mrow + r] * facc[i][j][r];
    }
  }
}

extern "C" void kernel_launch(void* const* d_in, const int* in_sizes, int n_in,
                              void* d_out, int out_size, void* d_ws,
                              size_t ws_size, hipStream_t stream) {
  const float* x = (const float*)d_in[0];
  const int* wq = (const int*)d_in[1];
  const float* wsc = (const float*)d_in[2];
  float* out = (float*)d_out;

  const size_t W8 = (size_t)NDIM * KDIM;      // 64 MB
  const size_t XQ = (size_t)MDIM * KDIM;      // 4 MB
  const size_t AX = 65536;                    // padded
  const size_t PS = (size_t)MDIM * NDIM * 4;  // 16 MB per partial

  char* w8 = (char*)d_ws;
  char* xq = (char*)d_ws + W8;
  float* ax = (float*)((char*)d_ws + W8 + XQ);
  float* part = (float*)((char*)d_ws + W8 + XQ + AX);

  produce_kernel<<<dim3(16384 + MDIM), dim3(256), 0, stream>>>(wq, x, w8, xq, ax);

  if (ws_size >= W8 + XQ + AX + 4 * PS) {
    gemm_i8_kernel<4><<<dim3(2048), dim3(256), 0, stream>>>(xq, w8, wsc, ax, part);
    reduce_kernel<4><<<dim3((MDIM * NDIM) / (256 * 4)), dim3(256), 0, stream>>>(part, out);
  } else if (ws_size >= W8 + XQ + AX + 2 * PS) {
    gemm_i8_kernel<2><<<dim3(1024), dim3(256), 0, stream>>>(xq, w8, wsc, ax, part);
    reduce_kernel<2><<<dim3((MDIM * NDIM) / (256 * 4)), dim3(256), 0, stream>>>(part, out);
  } else {
    gemm_i8_kernel<1><<<dim3(512), dim3(256), 0, stream>>>(xq, w8, wsc, ax, out);
  }
}

// Round 13
// 139.022 us; speedup vs baseline: 1.1451x; 1.1451x over previous
//
#include <hip/hip_runtime.h>

#define MDIM 512
#define NDIM 8192
#define KDIM 8192

typedef float v4f __attribute__((ext_vector_type(4)));
typedef int   v4i __attribute__((ext_vector_type(4)));
typedef char  c16 __attribute__((ext_vector_type(16)));

#define GLDS16(g, l)                                                    \
  __builtin_amdgcn_global_load_lds(                                     \
      (const __attribute__((address_space(1))) void*)(g),               \
      (__attribute__((address_space(3))) void*)(l), 16, 0, 0)
#define SB __builtin_amdgcn_sched_barrier(0)

// Swizzled byte offset inside a tile of 64B rows (BK=64 int8): rows paired
// into 128B blocks of 8x16B slots; slot XOR'd with row-pair (r8 scheme,
// measured 0 conflicts). Producers write this layout; glds copies linearly;
// gemm ds_read applies the same formula (rule 21: both sides).
__device__ __forceinline__ int swb(int row, int g) {
  return ((row >> 1) << 7) + (((((row & 1) << 2) | g) ^ ((row >> 1) & 7)) << 4);
}

// Merged producer:
//  blocks [0, 16384): wq int32 -> int8, tiled w8[nt128][kt128][4KB], swizzled.
//  blocks [16384, 16896): x fp32 -> int8 + per-row scale ax, xq tiled.
__global__ __launch_bounds__(256) void produce_kernel(
    const int* __restrict__ wq, const float* __restrict__ x,
    char* __restrict__ w8, char* __restrict__ xq, float* __restrict__ ax) {
  if (blockIdx.x < 16384) {
    const int tid = blockIdx.x * 256 + threadIdx.x;
    const int R = tid >> 9;     // weight row 0..8191
    const int k16 = tid & 511;  // 16-int group
    const int* src = wq + ((size_t)R << 13) + k16 * 16;
    v4i a[4];
#pragma unroll
    for (int h = 0; h < 4; ++h) a[h] = *(const v4i*)(src + h * 4);
    c16 q;
#pragma unroll
    for (int h = 0; h < 4; ++h) {
      q[h * 4 + 0] = (char)a[h][0];
      q[h * 4 + 1] = (char)a[h][1];
      q[h * 4 + 2] = (char)a[h][2];
      q[h * 4 + 3] = (char)a[h][3];
    }
    const int nt = R >> 6, r = R & 63;
    const int kt = k16 >> 2, g = k16 & 3;
    *(c16*)(w8 + ((size_t)(nt * 128 + kt) << 12) + swb(r, g)) = q;
  } else {
    const int m = blockIdx.x - 16384;
    const int t = threadIdx.x;
    const float* row = x + ((size_t)m << 13);
    v4f v[8];
    float mx = 0.f;
#pragma unroll
    for (int i = 0; i < 8; ++i) {
      v[i] = *(const v4f*)(row + t * 32 + i * 4);
#pragma unroll
      for (int r = 0; r < 4; ++r) mx = fmaxf(mx, fabsf(v[i][r]));
    }
#pragma unroll
    for (int d = 1; d < 64; d <<= 1) mx = fmaxf(mx, __shfl_xor(mx, d));
    __shared__ float smx[4];
    if ((t & 63) == 0) smx[t >> 6] = mx;
    __syncthreads();
    mx = fmaxf(fmaxf(smx[0], smx[1]), fmaxf(smx[2], smx[3]));
    const float inv = (mx > 0.f) ? 127.f / mx : 0.f;
    if (t == 0) ax[m] = mx / 127.f;
    const int mt = m >> 7, r = m & 127;
#pragma unroll
    for (int g2 = 0; g2 < 2; ++g2) {
      c16 q;
#pragma unroll
      for (int e = 0; e < 16; ++e) {
        const int idx = g2 * 4 + (e >> 2);
        float f = fminf(fmaxf(v[idx][e & 3] * inv, -127.f), 127.f);
        q[e] = (char)__float2int_rn(f);
      }
      const int k16 = t * 2 + g2;
      const int kt = k16 >> 2, g = k16 & 3;
      *(c16*)(xq + ((size_t)(mt * 128 + kt) << 13) + swb(r, g)) = q;
    }
  }
}

template <int KS>
__global__ __launch_bounds__(256) void reduce_kernel(const float* __restrict__ p,
                                                     float* __restrict__ out) {
  const size_t i = ((size_t)blockIdx.x * 256 + threadIdx.x) * 4;
  v4f a = *(const v4f*)(p + i);
#pragma unroll
  for (int s = 1; s < KS; ++s) a += *(const v4f*)(p + (size_t)s * MDIM * NDIM + i);
  *(v4f*)(out + i) = a;
}

// Pure-i8 GEMM, r8 sync structure, DOUBLED tile area (cache-BW lever):
// BM=128, BN=128, BK=64, 8 waves of 512-thread blocks (2m x 4n wave grid,
// wave tile 64x32 = r8's exact per-wave shape). Per phase per wave:
// 2 glds (1A+1B), 6 ds_read_b128, 8 mfma_i32_16x16x64_i8; counted vmcnt(2).
// Traffic 768->512MB. Scale-n row uniform per block (BN=128). KS split-K.
template <int KS>
__global__ __launch_bounds__(512) void gemm_i8_kernel(
    const char* __restrict__ xq, const char* __restrict__ w8,
    const float* __restrict__ wsc, const float* __restrict__ ax,
    float* __restrict__ outp) {
  constexpr int NKT = 128 / KS;  // k64 phases per block (even)
  __shared__ char lA[2][8192];
  __shared__ char lB[2][8192];

  // XCD swizzle: XCD c owns nt2 in [c*8, c*8+8) x all mt,kh.
  const int b = blockIdx.x;
  const int c = b & 7;
  const int s = b >> 3;
  const int mt = s & 3;
  const int kh = (KS > 1) ? ((s >> 2) & (KS - 1)) : 0;
  const int nt2 = c * 8 + ((KS > 1) ? (s >> 3) : (s >> 2));
  const int m0 = mt * 128, n0 = nt2 * 128;
  const int kt0 = kh * NKT;  // k64-tile base

  const int t = threadIdx.x;
  const int w = t >> 6, l = t & 63;       // 8 waves
  const int wm = (w >> 2) * 64;           // 2 m-halves
  const int wn = (w & 3) * 32;            // 4 n-quarters
  const int l15 = l & 15, q = l >> 4;

  // per-wave glds sources: wave w stages A 1KB (8KB tile) and B 1KB
  // (two 4KB w8 tiles: waves 0-3 -> n-rows 0-63, waves 4-7 -> 64-127)
  const char* aS = xq + ((size_t)(mt * 128 + kt0) << 13) + (size_t)(w * 64 + l) * 16;
  const char* bS = w8 + ((size_t)((nt2 * 2 + (w >> 2)) * 128 + kt0) << 12) +
                   (size_t)((w & 3) * 64 + l) * 16;

  v4i acc[4][2] = {};
  v4f facc[4][2] = {};

  auto issue = [&](int tt) {
    const int buf = tt & 1;
    GLDS16(aS + ((size_t)tt << 13), &lA[buf][w * 1024]);
    GLDS16(bS + ((size_t)tt << 12), &lB[buf][w * 1024]);
  };

  issue(0);
#pragma unroll 1
  for (int tt = 0; tt < NKT; ++tt) {
    const int cur = tt & 1;
    SB;
    __builtin_amdgcn_s_barrier();  // all waves done reading buf[cur^1]
    SB;
    if (tt + 1 < NKT) issue(tt + 1);  // -> buf[cur^1], stays in flight
    SB;
    if (tt + 1 < NKT)
      asm volatile("s_waitcnt vmcnt(2)" ::: "memory");  // tile tt landed
    else
      asm volatile("s_waitcnt vmcnt(0)" ::: "memory");
    SB;
    __builtin_amdgcn_s_barrier();  // buf[cur] visible to all waves
    SB;

    v4i af[4], bq[2];
#pragma unroll
    for (int i = 0; i < 4; ++i)
      af[i] = *(const v4i*)&lA[cur][swb(wm + i * 16 + l15, q)];
#pragma unroll
    for (int j = 0; j < 2; ++j) {
      const int rl = (wn & 63) + j * 16 + l15;  // row within 64-row sub-tile
      bq[j] = *(const v4i*)&lB[cur][(wn >> 6) * 4096 + swb(rl, q)];
    }
#pragma unroll
    for (int i = 0; i < 4; ++i)
#pragma unroll
      for (int j = 0; j < 2; ++j)
        acc[i][j] = __builtin_amdgcn_mfma_i32_16x16x64_i8(
            af[i], bq[j], acc[i][j], 0, 0, 0);

    if (tt & 1) {  // per-k128 scale block -> fold into f32 accumulator
      const float sc = wsc[nt2 * 64 + ((kt0 + tt) >> 1)];
#pragma unroll
      for (int i = 0; i < 4; ++i)
#pragma unroll
        for (int j = 0; j < 2; ++j) {
#pragma unroll
          for (int r = 0; r < 4; ++r)
            facc[i][j][r] = fmaf(sc, (float)acc[i][j][r], facc[i][j][r]);
          acc[i][j] = v4i{0, 0, 0, 0};
        }
    }
  }

  float* dst = outp + ((KS > 1) ? (size_t)kh * MDIM * NDIM : 0);
#pragma unroll
  for (int i = 0; i < 4; ++i) {
    const int mrow = m0 + wm + i * 16 + (l >> 4) * 4;
#pragma unroll
    for (int j = 0; j < 2; ++j) {
      const int ocol = n0 + wn + j * 16 + l15;
#pragma unroll
      for (int r = 0; r < 4; ++r)
        dst[(size_t)(mrow + r) * NDIM + ocol] = ax[mrow + r] * facc[i][j][r];
    }
  }
}

extern "C" void kernel_launch(void* const* d_in, const int* in_sizes, int n_in,
                              void* d_out, int out_size, void* d_ws,
                              size_t ws_size, hipStream_t stream) {
  const float* x = (const float*)d_in[0];
  const int* wq = (const int*)d_in[1];
  const float* wsc = (const float*)d_in[2];
  float* out = (float*)d_out;

  const size_t W8 = (size_t)NDIM * KDIM;      // 64 MB
  const size_t XQ = (size_t)MDIM * KDIM;      // 4 MB
  const size_t AX = 65536;                    // padded
  const size_t PS = (size_t)MDIM * NDIM * 4;  // 16 MB per partial

  char* w8 = (char*)d_ws;
  char* xq = (char*)d_ws + W8;
  float* ax = (float*)((char*)d_ws + W8 + XQ);
  float* part = (float*)((char*)d_ws + W8 + XQ + AX);

  produce_kernel<<<dim3(16384 + MDIM), dim3(256), 0, stream>>>(wq, x, w8, xq, ax);

  if (ws_size >= W8 + XQ + AX + 2 * PS) {
    gemm_i8_kernel<2><<<dim3(512), dim3(512), 0, stream>>>(xq, w8, wsc, ax, part);
    reduce_kernel<2><<<dim3((MDIM * NDIM) / (256 * 4)), dim3(256), 0, stream>>>(part, out);
  } else {
    gemm_i8_kernel<1><<<dim3(256), dim3(512), 0, stream>>>(xq, w8, wsc, ax, out);
  }
}

// Round 14
// 128.253 us; speedup vs baseline: 1.2412x; 1.0840x over previous
//
#include <hip/hip_runtime.h>

#define MDIM 512
#define NDIM 8192
#define KDIM 8192

typedef float v4f __attribute__((ext_vector_type(4)));
typedef int   v4i __attribute__((ext_vector_type(4)));
typedef char  c16 __attribute__((ext_vector_type(16)));

#define GLDS16(g, l)                                                    \
  __builtin_amdgcn_global_load_lds(                                     \
      (const __attribute__((address_space(1))) void*)(g),               \
      (__attribute__((address_space(3))) void*)(l), 16, 0, 0)
#define SB __builtin_amdgcn_sched_barrier(0)

// Swizzled byte offset inside a 64-row x 64B(k) int8 tile (4KB): rows paired
// into 128B blocks of 8x16B slots; slot XOR'd with row-pair (r8 scheme,
// measured 0 conflicts). Producers write this layout; glds copies linearly;
// gemm ds_read applies the same formula (rule 21: both sides).
__device__ __forceinline__ int swb(int row, int g) {
  return ((row >> 1) << 7) + (((((row & 1) << 2) | g) ^ ((row >> 1) & 7)) << 4);
}

// Merged producer:
//  blocks [0,16384): wq int32 -> int8, w8 tiles [ntile128][kt128][4KB].
//  blocks [16384,16896): x fp32 -> int8 + per-row scale ax,
//                        xq tiles [mt8][kt128][4KB] (64-row tiles).
__global__ __launch_bounds__(256) void produce_kernel(
    const int* __restrict__ wq, const float* __restrict__ x,
    char* __restrict__ w8, char* __restrict__ xq, float* __restrict__ ax) {
  if (blockIdx.x < 16384) {
    const int tid = blockIdx.x * 256 + threadIdx.x;
    const int R = tid >> 9;     // weight row 0..8191
    const int k16 = tid & 511;  // 16-int group
    const int* src = wq + ((size_t)R << 13) + k16 * 16;
    v4i a[4];
#pragma unroll
    for (int h = 0; h < 4; ++h) a[h] = *(const v4i*)(src + h * 4);
    c16 q;
#pragma unroll
    for (int h = 0; h < 4; ++h) {
      q[h * 4 + 0] = (char)a[h][0];
      q[h * 4 + 1] = (char)a[h][1];
      q[h * 4 + 2] = (char)a[h][2];
      q[h * 4 + 3] = (char)a[h][3];
    }
    const int ntile = R >> 6, r = R & 63;
    const int kt = k16 >> 2, g = k16 & 3;
    *(c16*)(w8 + ((size_t)(ntile * 128 + kt) << 12) + swb(r, g)) = q;
  } else {
    const int m = blockIdx.x - 16384;
    const int t = threadIdx.x;
    const float* row = x + ((size_t)m << 13);
    v4f v[8];
    float mx = 0.f;
#pragma unroll
    for (int i = 0; i < 8; ++i) {
      v[i] = *(const v4f*)(row + t * 32 + i * 4);
#pragma unroll
      for (int r = 0; r < 4; ++r) mx = fmaxf(mx, fabsf(v[i][r]));
    }
#pragma unroll
    for (int d = 1; d < 64; d <<= 1) mx = fmaxf(mx, __shfl_xor(mx, d));
    __shared__ float smx[4];
    if ((t & 63) == 0) smx[t >> 6] = mx;
    __syncthreads();
    mx = fmaxf(fmaxf(smx[0], smx[1]), fmaxf(smx[2], smx[3]));
    const float inv = (mx > 0.f) ? 127.f / mx : 0.f;
    if (t == 0) ax[m] = mx / 127.f;
    const int mt = m >> 6, r = m & 63;  // 64-row xq tiles
#pragma unroll
    for (int g2 = 0; g2 < 2; ++g2) {
      c16 q;
#pragma unroll
      for (int e = 0; e < 16; ++e) {
        const int idx = g2 * 4 + (e >> 2);
        float f = fminf(fmaxf(v[idx][e & 3] * inv, -127.f), 127.f);
        q[e] = (char)__float2int_rn(f);
      }
      const int k16 = t * 2 + g2;
      const int kt = k16 >> 2, g = k16 & 3;
      *(c16*)(xq + ((size_t)(mt * 128 + kt) << 12) + swb(r, g)) = q;
    }
  }
}

// Pure-i8 GEMM, KS=1 (no partials, no reduce): BM=64, BN=128, BK=128,
// 8 waves (wave tile 32x32), 64 phases, LDS 48KB dbuf -> 3 blocks/CU.
// Per phase/wave: 3 glds, 8 ds_read_b128, 8 mfma_i32_16x16x64_i8,
// 1 scale-fold (BK=128 == one k-scale block). Counted vmcnt(3).
__global__ __launch_bounds__(512, 1) void gemm_i8_kernel(
    const char* __restrict__ xq, const char* __restrict__ w8,
    const float* __restrict__ wsc, const float* __restrict__ ax,
    float* __restrict__ out) {
  constexpr int NPH = 64;          // k128 phases
  __shared__ char lA[2][8192];     // 2 ktiles (A: 64 rows x 128k)
  __shared__ char lB[2][16384];    // 4 tiles (B: 128 rows x 128k)

  // Chunked XCD swizzle: XCD c gets 64 consecutive blocks = nt2 in
  // [c*8, c*8+8), mt inner -> 8 mt-blocks of one nt2 co-resident, B panel
  // (1MB) shared in that XCD's L2.
  const int b = blockIdx.x;
  const int c = b & 7;
  const int s = b >> 3;
  const int mt = s & 7;
  const int nt2 = c * 8 + (s >> 3);
  const int m0 = mt * 64, n0 = nt2 * 128;

  const int t = threadIdx.x;
  const int w = t >> 6, l = t & 63;
  const int wm = (w >> 2) * 32;  // 2 m-halves
  const int wn = (w & 3) * 32;   // 4 n-quarters
  const int l15 = l & 15, q = l >> 4;

  v4i acc[2][2] = {};
  v4f facc[2][2] = {};

  // staging: 6 regions of 4KB per phase (A: kt pair; B: 2 ntiles x kt pair),
  // each region = 4 wave-quarters; wave w covers units w*3..w*3+2.
  auto issue = [&](int tt) {
    const int buf = tt & 1;
#pragma unroll
    for (int it = 0; it < 3; ++it) {
      const int u = w * 3 + it;
      const int reg = u >> 2, qt = u & 3;
      const char* src;
      if (reg < 2) {
        src = xq + ((size_t)(mt * 128 + tt * 2 + reg) << 12);
      } else {
        const int nh = (reg - 2) >> 1, kh = (reg - 2) & 1;
        src = w8 + ((size_t)((nt2 * 2 + nh) * 128 + tt * 2 + kh) << 12);
      }
      src += qt * 1024 + (size_t)l * 16;
      if (reg < 2)
        GLDS16(src, &lA[buf][reg * 4096 + qt * 1024]);
      else
        GLDS16(src, &lB[buf][(reg - 2) * 4096 + qt * 1024]);
    }
  };

  issue(0);
#pragma unroll 1
  for (int tt = 0; tt < NPH; ++tt) {
    const int cur = tt & 1;
    SB;
    __builtin_amdgcn_s_barrier();  // all waves done reading buf[cur^1]
    SB;
    if (tt + 1 < NPH) issue(tt + 1);  // -> buf[cur^1], stays in flight
    SB;
    if (tt + 1 < NPH)
      asm volatile("s_waitcnt vmcnt(3)" ::: "memory");  // phase tt landed
    else
      asm volatile("s_waitcnt vmcnt(0)" ::: "memory");
    SB;
    __builtin_amdgcn_s_barrier();  // buf[cur] visible to all waves
    SB;

#pragma unroll
    for (int kk = 0; kk < 2; ++kk) {  // two k64 sub-tiles of the phase
      v4i af[2], bq[2];
#pragma unroll
      for (int i = 0; i < 2; ++i)
        af[i] = *(const v4i*)&lA[cur][kk * 4096 + swb(wm + i * 16 + l15, q)];
#pragma unroll
      for (int j = 0; j < 2; ++j) {
        const int rb = wn + j * 16 + l15;  // 0..127
        bq[j] = *(const v4i*)&lB[cur][(rb >> 6) * 8192 + kk * 4096 +
                                      swb(rb & 63, q)];
      }
#pragma unroll
      for (int i = 0; i < 2; ++i)
#pragma unroll
        for (int j = 0; j < 2; ++j)
          acc[i][j] = __builtin_amdgcn_mfma_i32_16x16x64_i8(
              af[i], bq[j], acc[i][j], 0, 0, 0);
    }

    const float sc = wsc[nt2 * 64 + tt];  // one (n128,k128) scale block
#pragma unroll
    for (int i = 0; i < 2; ++i)
#pragma unroll
      for (int j = 0; j < 2; ++j) {
#pragma unroll
        for (int r = 0; r < 4; ++r)
          facc[i][j][r] = fmaf(sc, (float)acc[i][j][r], facc[i][j][r]);
        acc[i][j] = v4i{0, 0, 0, 0};
      }
  }

#pragma unroll
  for (int i = 0; i < 2; ++i) {
    const int mrow = m0 + wm + i * 16 + q * 4;
#pragma unroll
    for (int j = 0; j < 2; ++j) {
      const int ocol = n0 + wn + j * 16 + l15;
#pragma unroll
      for (int r = 0; r < 4; ++r)
        out[(size_t)(mrow + r) * NDIM + ocol] = ax[mrow + r] * facc[i][j][r];
    }
  }
}

extern "C" void kernel_launch(void* const* d_in, const int* in_sizes, int n_in,
                              void* d_out, int out_size, void* d_ws,
                              size_t ws_size, hipStream_t stream) {
  const float* x = (const float*)d_in[0];
  const int* wq = (const int*)d_in[1];
  const float* wsc = (const float*)d_in[2];
  float* out = (float*)d_out;

  const size_t W8 = (size_t)NDIM * KDIM;  // 64 MB
  const size_t XQ = (size_t)MDIM * KDIM;  // 4 MB

  char* w8 = (char*)d_ws;
  char* xq = (char*)d_ws + W8;
  float* ax = (float*)((char*)d_ws + W8 + XQ);

  produce_kernel<<<dim3(16384 + MDIM), dim3(256), 0, stream>>>(wq, x, w8, xq, ax);
  gemm_i8_kernel<<<dim3(512), dim3(512), 0, stream>>>(xq, w8, wsc, ax, out);
}